// Round 8
// baseline (14563.600 us; speedup 1.0000x reference)
//
#include <hip/hip_runtime.h>
#include <math.h>

// ---------------- problem constants ----------------
#define TS   2048   // timesteps
#define NN   100    // nodes
#define FD   128    // input features
#define HD   512    // hidden
#define NGR  8      // node groups (13 nodes each, 16-row padded stripes)
#define NBS  13     // nodes per group
#define NSL  8      // hidden slices (64 h-cols each)
#define KNN  8
#define GIN  704    // HD + 64 + 128
#define GH   256
#define GOUT 128

typedef float  f32x4  __attribute__((ext_vector_type(4)));
typedef __bf16 bf16x8 __attribute__((ext_vector_type(8)));
#define MFMA16(a, b, c) __builtin_amdgcn_mfma_f32_16x16x32_bf16((a), (b), (c), 0, 0, 0)

#define WXST 136   // Wx/Ax LDS row stride (bf16): 272B, 16B-aligned

__device__ __forceinline__ float sig_(float v) {
    return __builtin_amdgcn_rcpf(1.f + __expf(-v));
}
__device__ __forceinline__ float tanh_(float v) {
    float e = __expf(2.f * v);
    return 1.f - 2.f * __builtin_amdgcn_rcpf(e + 1.f);   // saturates at +/-1
}

// ---------- agent-scope (LLC-coherent, sc0 sc1) memory helpers ----------
// This is the r3/r5-proven protocol. XCD-local (sc0-only) mode is abandoned:
// it deadlocked twice when it actually engaged (r6/r7).

__device__ __forceinline__ void loadh16_a(const __bf16* base, unsigned voff, f32x4* h) {
    asm volatile(
        "global_load_dwordx4 %0, %16, %17 sc0 sc1\n\t"
        "global_load_dwordx4 %1, %16, %17 offset:64 sc0 sc1\n\t"
        "global_load_dwordx4 %2, %16, %17 offset:128 sc0 sc1\n\t"
        "global_load_dwordx4 %3, %16, %17 offset:192 sc0 sc1\n\t"
        "global_load_dwordx4 %4, %16, %17 offset:256 sc0 sc1\n\t"
        "global_load_dwordx4 %5, %16, %17 offset:320 sc0 sc1\n\t"
        "global_load_dwordx4 %6, %16, %17 offset:384 sc0 sc1\n\t"
        "global_load_dwordx4 %7, %16, %17 offset:448 sc0 sc1\n\t"
        "global_load_dwordx4 %8, %16, %17 offset:512 sc0 sc1\n\t"
        "global_load_dwordx4 %9, %16, %17 offset:576 sc0 sc1\n\t"
        "global_load_dwordx4 %10, %16, %17 offset:640 sc0 sc1\n\t"
        "global_load_dwordx4 %11, %16, %17 offset:704 sc0 sc1\n\t"
        "global_load_dwordx4 %12, %16, %17 offset:768 sc0 sc1\n\t"
        "global_load_dwordx4 %13, %16, %17 offset:832 sc0 sc1\n\t"
        "global_load_dwordx4 %14, %16, %17 offset:896 sc0 sc1\n\t"
        "global_load_dwordx4 %15, %16, %17 offset:960 sc0 sc1\n\t"
        "s_waitcnt vmcnt(0)"
        : "=&v"(h[0]), "=&v"(h[1]), "=&v"(h[2]), "=&v"(h[3]),
          "=&v"(h[4]), "=&v"(h[5]), "=&v"(h[6]), "=&v"(h[7]),
          "=&v"(h[8]), "=&v"(h[9]), "=&v"(h[10]), "=&v"(h[11]),
          "=&v"(h[12]), "=&v"(h[13]), "=&v"(h[14]), "=&v"(h[15])
        : "v"(voff), "s"(base) : "memory");
}

// 4 row-stores (row stride 1024B = HD*2), NO waitcnt: caller overlaps the ack.
__device__ __forceinline__ void storeh4_a(__bf16* base, unsigned voff,
                                          unsigned v0, unsigned v1, unsigned v2, unsigned v3) {
    asm volatile(
        "global_store_short %4, %0, %5 sc0 sc1\n\t"
        "global_store_short %4, %1, %5 offset:1024 sc0 sc1\n\t"
        "global_store_short %4, %2, %5 offset:2048 sc0 sc1\n\t"
        "global_store_short %4, %3, %5 offset:3072 sc0 sc1"
        :: "v"(v0), "v"(v1), "v"(v2), "v"(v3), "v"(voff), "s"(base) : "memory");
}

__device__ __forceinline__ void tagstore_a(int* base, unsigned voff, int val) {
    asm volatile("global_store_dword %1, %0, %2 sc0 sc1"
                 :: "v"(val), "v"(voff), "s"(base) : "memory");
}
// NOTE: trailing vmcnt(0) also drains any in-flight h stores -> free ack overlap.
__device__ __forceinline__ int tagload_a(const int* base, unsigned voff) {
    int v;
    asm volatile("global_load_dword %0, %1, %2 sc0 sc1\n\ts_waitcnt vmcnt(0)"
                 : "=v"(v) : "v"(voff), "s"(base) : "memory");
    return v;
}

__device__ __forceinline__ bf16x8 cvt8(const float* p) {
    float4 a = *(const float4*)p, b = *(const float4*)(p + 4);
    bf16x8 r;
    r[0] = (__bf16)a.x; r[1] = (__bf16)a.y; r[2] = (__bf16)a.z; r[3] = (__bf16)a.w;
    r[4] = (__bf16)b.x; r[5] = (__bf16)b.y; r[6] = (__bf16)b.z; r[7] = (__bf16)b.w;
    return r;
}

// =====================================================================
// Persistent GRU, dual-chain software pipeline. Grid = 32 blocks x 256.
// block b: pair p=b>>3 (groups gA=2p, gB=2p+1), slice s=b&7 (h-cols
// [64s,64s+64); wave w owns 16 cols). Whh B-frags (48 = 192 VGPR) are
// SHARED by both chains (weights depend on cols only). Per iteration
// (= 2 GRU steps, one per chain): pollA -> loadA -> mfmaA -> gatesA ->
// issue A-stores (no wait) -> pollB (its vmcnt(0) absorbs A's ack) ->
// loadB -> mfmaB -> gatesB -> B-stores -> one ack -> one barrier ->
// both tags -> slack window (stage x_{t+1} A+B, x-part MFMAs).
// h buffers use 16-row stripes per group (rows 13..15 pad, never read
// as real nodes) so pad stores can't collide across groups.
// =====================================================================
__global__ __launch_bounds__(256, 1) void gru_kernel(
    const float* __restrict__ x,     // [TS, NN, FD]
    const float* __restrict__ Wih,   // [3H, FD]
    const float* __restrict__ Whh,   // [3H, HD]
    const float* __restrict__ bih,   // [3H]
    const float* __restrict__ bhh,   // [3H]
    __bf16* __restrict__ h0buf,      // [128, HD] bf16, zero-init (h0)
    __bf16* __restrict__ h1buf,      // [128, HD] bf16
    float*  __restrict__ enc,        // [NN, HD] fp32, final h
    int*    __restrict__ tags)       // 64 slots x 64B, zero-init
{
    const int bid = blockIdx.x;
    const int p   = bid >> 3;        // pair 0..3
    const int s   = bid & 7;         // slice 0..7
    const int gA  = 2 * p, gB = 2 * p + 1;
    const int tid = threadIdx.x;
    const int w   = tid >> 6;        // wave 0..3
    const int ln  = tid & 63;
    const int mi  = ln & 15;
    const int kq8 = (ln >> 4) * 8;
    const int cl  = 16 * w + mi;     // col local 0..63
    const int ch  = 64 * s + cl;     // global h col

    __shared__ __align__(16) __bf16 Wx[192 * WXST];      // Wih slice (shared A/B)
    __shared__ __align__(16) __bf16 Ax[2 * 32 * WXST];   // x tiles: [slot][32 rows]

    // ---- one-time: Wih slice -> LDS ----
    for (int idx = tid; idx < 192 * 32; idx += 256) {
        int row = idx >> 5, c4 = idx & 31;
        int grow = (row >> 6) * HD + 64 * s + (row & 63);
        float4 v = ((const float4*)(Wih + (size_t)grow * FD))[c4];
        __bf16* d = Wx + row * WXST + c4 * 4;
        d[0] = (__bf16)v.x; d[1] = (__bf16)v.y; d[2] = (__bf16)v.z; d[3] = (__bf16)v.w;
    }

    // ---- one-time: Whh B-frags -> registers (shared by both chains) ----
    bf16x8 wR[16], wZ[16], wN[16];
    {
        const float* pR = Whh + (size_t)ch * HD;
        const float* pZ = Whh + (size_t)(HD + ch) * HD;
        const float* pN = Whh + (size_t)(2 * HD + ch) * HD;
        #pragma unroll
        for (int kk = 0; kk < 16; ++kk) {
            int ko = 32 * kk + kq8;
            wR[kk] = cvt8(pR + ko);
            wZ[kk] = cvt8(pZ + ko);
            wN[kk] = cvt8(pN + ko);
        }
    }
    const float bR  = bih[ch] + bhh[ch];
    const float bZ  = bih[HD + ch] + bhh[HD + ch];
    const float bNX = bih[2 * HD + ch];
    const float bNH = bhh[2 * HD + ch];

    // x staging lane mapping: 16 rows x 16 segs of 8 floats, per group
    const int xrow  = tid >> 4;
    const int xseg  = (tid & 15) * 8;
    const int xnodeA = NBS * gA + xrow;     // may spill into next group: harmless
    const int xnodeB = NBS * gB + xrow;

    // ---- addressing ----
    const unsigned hvA = ((unsigned)(16 * gA + mi) * HD + (unsigned)kq8) * 2u;
    const unsigned hvB = ((unsigned)(16 * gB + mi) * HD + (unsigned)kq8) * 2u;
    const unsigned stA = ((unsigned)(16 * gA + (ln >> 4) * 4) * HD + (unsigned)ch) * 2u;
    const unsigned stB = ((unsigned)(16 * gB + (ln >> 4) * 4) * HD + (unsigned)ch) * 2u;
    const unsigned tgA_self = (unsigned)(gA * NSL + s) * 64u;        // byte offsets
    const unsigned tgB_self = (unsigned)(gB * NSL + s) * 64u;
    const unsigned tgA_poll = (unsigned)(gA * NSL + (ln & 7)) * 64u;
    const unsigned tgB_poll = (unsigned)(gB * NSL + (ln & 7)) * 64u;

    // ---- prologue: stage x_0 (A+B), x-part MFMAs for t=0 ----
    {
        float4 a0 = {0.f, 0.f, 0.f, 0.f}, a1 = a0, b0 = a0, b1 = a0;
        if (xnodeA < NN) {
            const float* xp = x + (size_t)xnodeA * FD + xseg;
            a0 = ((const float4*)xp)[0]; a1 = ((const float4*)xp)[1];
        }
        if (xnodeB < NN) {
            const float* xp = x + (size_t)xnodeB * FD + xseg;
            b0 = ((const float4*)xp)[0]; b1 = ((const float4*)xp)[1];
        }
        bf16x8 va, vb;
        va[0]=(__bf16)a0.x; va[1]=(__bf16)a0.y; va[2]=(__bf16)a0.z; va[3]=(__bf16)a0.w;
        va[4]=(__bf16)a1.x; va[5]=(__bf16)a1.y; va[6]=(__bf16)a1.z; va[7]=(__bf16)a1.w;
        vb[0]=(__bf16)b0.x; vb[1]=(__bf16)b0.y; vb[2]=(__bf16)b0.z; vb[3]=(__bf16)b0.w;
        vb[4]=(__bf16)b1.x; vb[5]=(__bf16)b1.y; vb[6]=(__bf16)b1.z; vb[7]=(__bf16)b1.w;
        *(bf16x8*)(Ax + (size_t)xrow * WXST + xseg) = va;
        *(bf16x8*)(Ax + (size_t)(16 + xrow) * WXST + xseg) = vb;
    }
    __syncthreads();

    f32x4 aRA = {0.f,0.f,0.f,0.f}, aZA = aRA, aNXA = aRA, aNHA = aRA;
    f32x4 aRB = aRA, aZB = aRA, aNXB = aRA, aNHB = aRA;
    #pragma unroll
    for (int kk = 0; kk < 4; ++kk) {
        int ko = 32 * kk + kq8;
        bf16x8 avA = *(const bf16x8*)(Ax + (size_t)mi * WXST + ko);
        bf16x8 avB = *(const bf16x8*)(Ax + (size_t)(16 + mi) * WXST + ko);
        const bf16x8 wr = *(const bf16x8*)(Wx + (size_t)cl * WXST + ko);
        const bf16x8 wz = *(const bf16x8*)(Wx + (size_t)(64 + cl) * WXST + ko);
        const bf16x8 wn = *(const bf16x8*)(Wx + (size_t)(128 + cl) * WXST + ko);
        aRA  = MFMA16(avA, wr, aRA);  aRB  = MFMA16(avB, wr, aRB);
        aZA  = MFMA16(avA, wz, aZA);  aZB  = MFMA16(avB, wz, aZB);
        aNXA = MFMA16(avA, wn, aNXA); aNXB = MFMA16(avB, wn, aNXB);
    }

    float holdA[4] = {0.f,0.f,0.f,0.f}, holdB[4] = {0.f,0.f,0.f,0.f};

    #pragma unroll 1
    for (int t = 0; t < TS; ++t) {
        __bf16* hcur = (t & 1) ? h1buf : h0buf;
        __bf16* hnxt = (t & 1) ? h0buf : h1buf;

        // ================= chain A =================
        for (;;) {
            int v = tagload_a(tags, tgA_poll);
            if (__all((ln < 8) ? (v >= t) : 1)) break;
        }
        {
            f32x4 hv[16];
            loadh16_a(hcur, hvA, hv);
            #pragma unroll
            for (int kk = 0; kk < 16; ++kk) {
                bf16x8 av = __builtin_bit_cast(bf16x8, hv[kk]);
                aRA  = MFMA16(av, wR[kk], aRA);
                aZA  = MFMA16(av, wZ[kk], aZA);
                aNHA = MFMA16(av, wN[kk], aNHA);
            }
        }
        {
            unsigned pv[4];
            #pragma unroll
            for (int e = 0; e < 4; ++e) {
                float rv = sig_(aRA[e] + bR);
                float zv = sig_(aZA[e] + bZ);
                float nv = tanh_(aNXA[e] + bNX + rv * (aNHA[e] + bNH));
                float hnew = (1.f - zv) * nv + zv * holdA[e];
                holdA[e] = hnew;
                pv[e] = (unsigned)__builtin_bit_cast(unsigned short, (__bf16)hnew);
            }
            storeh4_a(hnxt, stA, pv[0], pv[1], pv[2], pv[3]);   // in flight
        }

        // ================= chain B (poll absorbs A's store ack) =================
        for (;;) {
            int v = tagload_a(tags, tgB_poll);
            if (__all((ln < 8) ? (v >= t) : 1)) break;
        }
        {
            f32x4 hv[16];
            loadh16_a(hcur, hvB, hv);
            #pragma unroll
            for (int kk = 0; kk < 16; ++kk) {
                bf16x8 av = __builtin_bit_cast(bf16x8, hv[kk]);
                aRB  = MFMA16(av, wR[kk], aRB);
                aZB  = MFMA16(av, wZ[kk], aZB);
                aNHB = MFMA16(av, wN[kk], aNHB);
            }
        }
        {
            unsigned pv[4];
            #pragma unroll
            for (int e = 0; e < 4; ++e) {
                float rv = sig_(aRB[e] + bR);
                float zv = sig_(aZB[e] + bZ);
                float nv = tanh_(aNXB[e] + bNX + rv * (aNHB[e] + bNH));
                float hnew = (1.f - zv) * nv + zv * holdB[e];
                holdB[e] = hnew;
                pv[e] = (unsigned)__builtin_bit_cast(unsigned short, (__bf16)hnew);
            }
            storeh4_a(hnxt, stB, pv[0], pv[1], pv[2], pv[3]);
        }

        asm volatile("s_waitcnt vmcnt(0)" ::: "memory");   // both strips acked at LLC
        __syncthreads();                                   // all 4 waves acked
        if (tid == 0) {
            tagstore_a(tags, tgA_self, t + 1);
            tagstore_a(tags, tgB_self, t + 1);
        }

        // ============ slack window: stage x_{t+1} (A+B) + x-part MFMAs ============
        const int nslot = (t + 1) & 1;
        if (t + 1 < TS) {
            const float* xt = x + (size_t)(t + 1) * NN * FD;
            float4 a0 = {0.f,0.f,0.f,0.f}, a1 = a0, b0 = a0, b1 = a0;
            if (xnodeA < NN) {
                const float* xp = xt + (size_t)xnodeA * FD + xseg;
                a0 = ((const float4*)xp)[0]; a1 = ((const float4*)xp)[1];
            }
            if (xnodeB < NN) {
                const float* xp = xt + (size_t)xnodeB * FD + xseg;
                b0 = ((const float4*)xp)[0]; b1 = ((const float4*)xp)[1];
            }
            bf16x8 va, vb;
            va[0]=(__bf16)a0.x; va[1]=(__bf16)a0.y; va[2]=(__bf16)a0.z; va[3]=(__bf16)a0.w;
            va[4]=(__bf16)a1.x; va[5]=(__bf16)a1.y; va[6]=(__bf16)a1.z; va[7]=(__bf16)a1.w;
            vb[0]=(__bf16)b0.x; vb[1]=(__bf16)b0.y; vb[2]=(__bf16)b0.z; vb[3]=(__bf16)b0.w;
            vb[4]=(__bf16)b1.x; vb[5]=(__bf16)b1.y; vb[6]=(__bf16)b1.z; vb[7]=(__bf16)b1.w;
            *(bf16x8*)(Ax + ((size_t)nslot * 32 + xrow) * WXST + xseg) = va;
            *(bf16x8*)(Ax + ((size_t)nslot * 32 + 16 + xrow) * WXST + xseg) = vb;
        }
        __syncthreads();

        aRA = {0.f,0.f,0.f,0.f}; aZA = aRA; aNXA = aRA; aNHA = aRA;
        aRB = aRA; aZB = aRA; aNXB = aRA; aNHB = aRA;
        if (t + 1 < TS) {
            #pragma unroll
            for (int kk = 0; kk < 4; ++kk) {
                int ko = 32 * kk + kq8;
                bf16x8 avA = *(const bf16x8*)(Ax + ((size_t)nslot * 32 + mi) * WXST + ko);
                bf16x8 avB = *(const bf16x8*)(Ax + ((size_t)nslot * 32 + 16 + mi) * WXST + ko);
                const bf16x8 wr = *(const bf16x8*)(Wx + (size_t)cl * WXST + ko);
                const bf16x8 wz = *(const bf16x8*)(Wx + (size_t)(64 + cl) * WXST + ko);
                const bf16x8 wn = *(const bf16x8*)(Wx + (size_t)(128 + cl) * WXST + ko);
                aRA  = MFMA16(avA, wr, aRA);  aRB  = MFMA16(avB, wr, aRB);
                aZA  = MFMA16(avA, wz, aZA);  aZB  = MFMA16(avB, wz, aZB);
                aNXA = MFMA16(avA, wn, aNXA); aNXB = MFMA16(avB, wn, aNXB);
            }
        }
    }

    // ---- epilogue: final h -> enc (fp32), valid rows only ----
    #pragma unroll
    for (int e = 0; e < 4; ++e) {
        int row = (ln >> 4) * 4 + e;
        int nA = NBS * gA + row, nB = NBS * gB + row;
        if (row < NBS && nA < NN) enc[(size_t)nA * HD + ch] = holdA[e];
        if (row < NBS && nB < NN) enc[(size_t)nB * HD + ch] = holdB[e];
    }
}

// ===================== epilogue (tiny) =====================

__global__ void e1_gnn_in(const float* __restrict__ enc, const float* __restrict__ flat,
                          const float* __restrict__ emb, const float* __restrict__ fW,
                          const float* __restrict__ fb, float* __restrict__ gnn)
{
    int i = blockIdx.x, tid = threadIdx.x;
    const float4* src = (const float4*)(enc + (size_t)i * HD);
    float4* dst = (float4*)(gnn + (size_t)i * GIN);
    dst[tid] = src[tid];
    if (tid < 64) {
        float acc = fb[tid];
        const float* w  = fW + tid * 32;
        const float* fl = flat + i * 32;
        #pragma unroll
        for (int k = 0; k < 32; ++k) acc = fmaf(fl[k], w[k], acc);
        gnn[(size_t)i * GIN + HD + tid] = acc;
    }
    gnn[(size_t)i * GIN + HD + 64 + tid] = emb[(size_t)i * FD + tid];
}

__global__ void e2a_norm(const float* __restrict__ emb, float* __restrict__ mx)
{
    int j = threadIdx.x;
    if (j < NN) {
        float acc = 0.f;
        const float* e = emb + (size_t)j * FD;
        for (int d = 0; d < FD; ++d) acc = fmaf(e[d], e[d], acc);
        mx[j] = fmaxf(sqrtf(acc), 1e-8f);
    }
}

__global__ void e2b_knn(const float* __restrict__ emb, const float* __restrict__ mx,
                        int* __restrict__ tgt)
{
    int i = blockIdx.x, tid = threadIdx.x;   // 128 threads
    __shared__ float ei[FD];
    __shared__ float srow[NN];
    ei[tid] = emb[(size_t)i * FD + tid];
    __syncthreads();
    if (tid < NN) {
        float acc = 0.f;
        const float* e = emb + (size_t)tid * FD;
        for (int d = 0; d < FD; ++d) acc = fmaf(ei[d], e[d], acc);
        float sim = acc / (mx[i] * mx[tid]);
        srow[tid] = (tid == i) ? 0.f : sim;
    }
    __syncthreads();
    if (tid == 0) {
        for (int t = 0; t < KNN; ++t) {
            float best = -1e30f; int bi = 0;
            for (int j = 0; j < NN; ++j) { float v = srow[j]; if (v > best) { best = v; bi = j; } }
            srow[bi] = -1e30f;
            tgt[i * KNN + t] = bi;
        }
    }
}

__global__ void e3_agg(const float* __restrict__ xin, const int* __restrict__ tgt,
                       float* __restrict__ agg, float* __restrict__ cnt, int D)
{
    int e = blockIdx.x, src = e >> 3, tg = tgt[e];
    for (int d = threadIdx.x; d < D; d += blockDim.x)
        atomicAdd(&agg[(size_t)tg * D + d], xin[(size_t)src * D + d]);
    if (threadIdx.x == 0) atomicAdd(&cnt[tg], 1.0f);
}

__global__ void e4_sage(const float* __restrict__ agg, const float* __restrict__ xin,
                        const float* __restrict__ cnt,
                        const float* __restrict__ Wl, const float* __restrict__ Wr,
                        const float* __restrict__ b, float* __restrict__ out,
                        int Din, int Dout, int dorelu)
{
    int j = blockIdx.x, o = threadIdx.x;
    extern __shared__ float sm[];
    float* la = sm;
    float* lx = sm + Din;
    for (int d = o; d < Din; d += blockDim.x) {
        la[d] = agg[(size_t)j * Din + d];
        lx[d] = xin[(size_t)j * Din + d];
    }
    __syncthreads();
    float inv = 1.f / fmaxf(cnt[j], 1.f);
    float acc1 = 0.f, acc2 = 0.f;
    const float* wl = Wl + (size_t)o * Din;
    const float* wr = Wr + (size_t)o * Din;
    for (int k = 0; k < Din; ++k) {
        acc1 = fmaf(la[k], wl[k], acc1);
        acc2 = fmaf(lx[k], wr[k], acc2);
    }
    float v = fmaf(acc1, inv, acc2) + b[o];
    if (dorelu) v = fmaxf(v, 0.f);
    out[(size_t)j * Dout + o] = v;
}

__global__ void e7_out(const float* __restrict__ g, const float* __restrict__ enc,
                       const float* __restrict__ oW, const float* __restrict__ ob,
                       float* __restrict__ out)
{
    int j = threadIdx.x;
    if (j < NN) {
        float acc = ob[0];
        const float* gr = g + (size_t)j * GOUT;
        for (int d = 0; d < GOUT; ++d) acc = fmaf(gr[d], oW[d], acc);
        const float* er = enc + (size_t)j * HD;
        for (int d = 0; d < HD; ++d) acc = fmaf(er[d], oW[GOUT + d], acc);
        out[j] = 1.f / (1.f + expf(-acc));
    }
}

// ===================== launch =====================
extern "C" void kernel_launch(void* const* d_in, const int* in_sizes, int n_in,
                              void* d_out, int out_size, void* d_ws, size_t ws_size,
                              hipStream_t stream)
{
    const float* x    = (const float*)d_in[0];
    const float* flat = (const float*)d_in[1];
    const float* emb  = (const float*)d_in[2];
    const float* Wih  = (const float*)d_in[3];
    const float* Whh  = (const float*)d_in[4];
    const float* bih  = (const float*)d_in[5];
    const float* bhh  = (const float*)d_in[6];
    const float* fW   = (const float*)d_in[7];
    const float* fb   = (const float*)d_in[8];
    const float* s1Wl = (const float*)d_in[9];
    const float* s1Wr = (const float*)d_in[10];
    const float* s1b  = (const float*)d_in[11];
    const float* s2Wl = (const float*)d_in[12];
    const float* s2Wr = (const float*)d_in[13];
    const float* s2b  = (const float*)d_in[14];
    const float* oW   = (const float*)d_in[15];
    const float* ob   = (const float*)d_in[16];
    float* out = (float*)d_out;

    // workspace layout (bytes). Zero zone first -> single memset.
    char* p = (char*)d_ws;
    __bf16* h0buf = (__bf16*)(p + 0);        // 131072  [zero: h0, 128x512]
    float*  agg1  = (float*)(p + 131072);    // 281600  [zero]
    float*  agg2  = (float*)(p + 412672);    // 102400  [zero]
    float*  cnt1  = (float*)(p + 515072);    // 448     [zero]
    float*  cnt2  = (float*)(p + 515520);    // 448     [zero]
    int*    tags  = (int*)  (p + 515968);    // 4096    [zero: 64 x 64B]
    __bf16* h1buf = (__bf16*)(p + 520064);   // 131072
    float*  enc   = (float*)(p + 651136);    // 204800 (100 x 512 fp32)
    float*  gnn   = (float*)(p + 855936);    // 281600
    float*  h1s   = (float*)(p + 1137536);   // 102400
    float*  gbuf  = (float*)(p + 1239936);   // 51200
    float*  mx    = (float*)(p + 1291136);   // 448
    int*    tgt   = (int*)  (p + 1291584);   // 3200
    // total ~1.29 MiB

    (void)hipMemsetAsync(d_ws, 0, 520064, stream);

    gru_kernel<<<32, 256, 0, stream>>>(x, Wih, Whh, bih, bhh, h0buf, h1buf, enc, tags);
    e1_gnn_in<<<NN, 128, 0, stream>>>(enc, flat, emb, fW, fb, gnn);
    e2a_norm<<<1, 128, 0, stream>>>(emb, mx);
    e2b_knn<<<NN, 128, 0, stream>>>(emb, mx, tgt);
    e3_agg<<<NN * KNN, 256, 0, stream>>>(gnn, tgt, agg1, cnt1, GIN);
    e4_sage<<<NN, GH, 2 * GIN * sizeof(float), stream>>>(agg1, gnn, cnt1, s1Wl, s1Wr, s1b, h1s, GIN, GH, 1);
    e3_agg<<<NN * KNN, 256, 0, stream>>>(h1s, tgt, agg2, cnt2, GH);
    e4_sage<<<NN, GOUT, 2 * GH * sizeof(float), stream>>>(agg2, h1s, cnt2, s2Wl, s2Wr, s2b, gbuf, GH, GOUT, 0);
    e7_out<<<1, 128, 0, stream>>>(gbuf, enc, oW, ob, out);
}

// Round 9
// 9842.609 us; speedup vs baseline: 1.4796x; 1.4796x over previous
//
#include <hip/hip_runtime.h>
#include <math.h>

// ---------------- problem constants ----------------
#define TS   2048   // timesteps
#define NN   100    // nodes
#define FD   128    // input features
#define HD   512    // hidden
#define NG   7      // node groups of 16
#define NSL  8      // hidden slices (64 h-cols each)
#define KNN  8
#define GIN  704    // HD + 64 + 128
#define GH   256
#define GOUT 128

typedef float  f32x4  __attribute__((ext_vector_type(4)));
typedef __bf16 bf16x8 __attribute__((ext_vector_type(8)));
#define MFMA16(a, b, c) __builtin_amdgcn_mfma_f32_16x16x32_bf16((a), (b), (c), 0, 0, 0)

#define WXST 136   // Wx LDS row stride (bf16): 272B, 16B-aligned

__device__ __forceinline__ float sig_(float v) {
    return __builtin_amdgcn_rcpf(1.f + __expf(-v));
}
__device__ __forceinline__ float tanh_(float v) {
    float e = __expf(2.f * v);
    return 1.f - 2.f * __builtin_amdgcn_rcpf(e + 1.f);   // saturates at +/-1
}

// ---------- agent-scope (LLC-coherent, sc0 sc1) memory helpers ----------
// r3/r5-proven protocol. XCD-local (sc0-only) mode abandoned: it deadlocked
// both times it engaged (r6/r7) regardless of engine structure.

__device__ __forceinline__ void loadh16_a(const __bf16* base, unsigned voff, f32x4* h) {
    asm volatile(
        "global_load_dwordx4 %0, %16, %17 sc0 sc1\n\t"
        "global_load_dwordx4 %1, %16, %17 offset:64 sc0 sc1\n\t"
        "global_load_dwordx4 %2, %16, %17 offset:128 sc0 sc1\n\t"
        "global_load_dwordx4 %3, %16, %17 offset:192 sc0 sc1\n\t"
        "global_load_dwordx4 %4, %16, %17 offset:256 sc0 sc1\n\t"
        "global_load_dwordx4 %5, %16, %17 offset:320 sc0 sc1\n\t"
        "global_load_dwordx4 %6, %16, %17 offset:384 sc0 sc1\n\t"
        "global_load_dwordx4 %7, %16, %17 offset:448 sc0 sc1\n\t"
        "global_load_dwordx4 %8, %16, %17 offset:512 sc0 sc1\n\t"
        "global_load_dwordx4 %9, %16, %17 offset:576 sc0 sc1\n\t"
        "global_load_dwordx4 %10, %16, %17 offset:640 sc0 sc1\n\t"
        "global_load_dwordx4 %11, %16, %17 offset:704 sc0 sc1\n\t"
        "global_load_dwordx4 %12, %16, %17 offset:768 sc0 sc1\n\t"
        "global_load_dwordx4 %13, %16, %17 offset:832 sc0 sc1\n\t"
        "global_load_dwordx4 %14, %16, %17 offset:896 sc0 sc1\n\t"
        "global_load_dwordx4 %15, %16, %17 offset:960 sc0 sc1\n\t"
        "s_waitcnt vmcnt(0)"
        : "=&v"(h[0]), "=&v"(h[1]), "=&v"(h[2]), "=&v"(h[3]),
          "=&v"(h[4]), "=&v"(h[5]), "=&v"(h[6]), "=&v"(h[7]),
          "=&v"(h[8]), "=&v"(h[9]), "=&v"(h[10]), "=&v"(h[11]),
          "=&v"(h[12]), "=&v"(h[13]), "=&v"(h[14]), "=&v"(h[15])
        : "v"(voff), "s"(base) : "memory");
}

// 4 row-stores (row stride 1024B = HD*2), NO waitcnt: ack overlapped by caller.
__device__ __forceinline__ void storeh4_a(__bf16* base, unsigned voff,
                                          unsigned v0, unsigned v1, unsigned v2, unsigned v3) {
    asm volatile(
        "global_store_short %4, %0, %5 sc0 sc1\n\t"
        "global_store_short %4, %1, %5 offset:1024 sc0 sc1\n\t"
        "global_store_short %4, %2, %5 offset:2048 sc0 sc1\n\t"
        "global_store_short %4, %3, %5 offset:3072 sc0 sc1"
        :: "v"(v0), "v"(v1), "v"(v2), "v"(v3), "v"(voff), "s"(base) : "memory");
}

__device__ __forceinline__ void tagstore_a(int* base, unsigned voff, int val) {
    asm volatile("global_store_dword %1, %0, %2 sc0 sc1"
                 :: "v"(val), "v"(voff), "s"(base) : "memory");
}
__device__ __forceinline__ int tagload_a(const int* base, unsigned voff) {
    int v;
    asm volatile("global_load_dword %0, %1, %2 sc0 sc1\n\ts_waitcnt vmcnt(0)"
                 : "=v"(v) : "v"(voff), "s"(base) : "memory");
    return v;
}

__device__ __forceinline__ bf16x8 cvt8(const float* p) {
    float4 a = *(const float4*)p, b = *(const float4*)(p + 4);
    bf16x8 r;
    r[0] = (__bf16)a.x; r[1] = (__bf16)a.y; r[2] = (__bf16)a.z; r[3] = (__bf16)a.w;
    r[4] = (__bf16)b.x; r[5] = (__bf16)b.y; r[6] = (__bf16)b.z; r[7] = (__bf16)b.w;
    return r;
}

__device__ __forceinline__ bf16x8 cvt8r(float4 a, float4 b) {
    bf16x8 r;
    r[0] = (__bf16)a.x; r[1] = (__bf16)a.y; r[2] = (__bf16)a.z; r[3] = (__bf16)a.w;
    r[4] = (__bf16)b.x; r[5] = (__bf16)b.y; r[6] = (__bf16)b.z; r[7] = (__bf16)b.w;
    return r;
}

// =====================================================================
// Persistent GRU, per-wave pipeline. Grid = 56 blocks x 256 (4 waves).
// block b: group g=b>>3 (nodes [16g,16g+16)), slice s=b&7; wave w owns
// h-cols [64s+16w, +16). Whh B-frags (48 = 192 VGPR) in registers; Wih
// in LDS (read-only after init); own h ("hold") in regs. Tags are
// PER-WAVE (32/group, 64B-padded, monotone). NO __syncthreads in the
// step loop: each wave polls all 32 tags >= t, loads h_t (bundled
// 16x dwordx4), 48 MFMA, gates, stores its strip, prefetches x_{t+1}
// (cached loads overlap the store ack), vmcnt(0), tags t+1, then runs
// the x-part MFMAs for t+1. Max wave skew = 1 step -> 2 h buffers.
// =====================================================================
__global__ __launch_bounds__(256, 1) void gru_kernel(
    const float* __restrict__ x,     // [TS, NN, FD]
    const float* __restrict__ Wih,   // [3H, FD]
    const float* __restrict__ Whh,   // [3H, HD]
    const float* __restrict__ bih,   // [3H]
    const float* __restrict__ bhh,   // [3H]
    __bf16* __restrict__ h0buf,      // [112, HD] bf16, zero-init (h0)
    __bf16* __restrict__ h1buf,      // [112, HD] bf16
    float*  __restrict__ enc,        // [112, HD] fp32, final h
    int*    __restrict__ tags)       // 224 slots x 64B, zero-init
{
    const int bid = blockIdx.x;
    const int g   = bid >> 3;        // node group 0..6
    const int s   = bid & 7;         // slice 0..7
    const int tid = threadIdx.x;
    const int w   = tid >> 6;        // wave 0..3
    const int ln  = tid & 63;
    const int nb  = g * 16;
    const int mi  = ln & 15;
    const int kq8 = (ln >> 4) * 8;
    const int cl  = 16 * w + mi;     // col local 0..63
    const int ch  = 64 * s + cl;     // global h col

    __shared__ __align__(16) __bf16 Wx[192 * WXST];   // Wih slice rows

    // ---- one-time: Wih slice -> LDS (192 gate rows x 128 K) ----
    for (int idx = tid; idx < 192 * 32; idx += 256) {
        int row = idx >> 5, c4 = idx & 31;
        int grow = (row >> 6) * HD + 64 * s + (row & 63);
        float4 v = ((const float4*)(Wih + (size_t)grow * FD))[c4];
        __bf16* d = Wx + row * WXST + c4 * 4;
        d[0] = (__bf16)v.x; d[1] = (__bf16)v.y; d[2] = (__bf16)v.z; d[3] = (__bf16)v.w;
    }

    // ---- one-time: Whh B-frags -> registers (48 frags = 192 VGPRs) ----
    bf16x8 wR[16], wZ[16], wN[16];
    {
        const float* pR = Whh + (size_t)ch * HD;
        const float* pZ = Whh + (size_t)(HD + ch) * HD;
        const float* pN = Whh + (size_t)(2 * HD + ch) * HD;
        #pragma unroll
        for (int kk = 0; kk < 16; ++kk) {
            int ko = 32 * kk + kq8;
            wR[kk] = cvt8(pR + ko);
            wZ[kk] = cvt8(pZ + ko);
            wN[kk] = cvt8(pN + ko);
        }
    }
    const float bR  = bih[ch] + bhh[ch];
    const float bZ  = bih[HD + ch] + bhh[HD + ch];
    const float bNX = bih[2 * HD + ch];
    const float bNH = bhh[2 * HD + ch];

    __syncthreads();   // Wx ready (the ONLY block barrier)

    const bool  xvalid = (nb + mi) < NN;
    const float* xrow0 = x + (size_t)(nb + mi) * FD;   // this lane's x row (t=0)

    // ---- prologue: x_0 loads + x-part MFMAs for t=0 ----
    f32x4 accR = {0.f, 0.f, 0.f, 0.f}, accZ = accR, accNX = accR, accNH = accR;
    {
        float4 xq[8];
        #pragma unroll
        for (int kk = 0; kk < 4; ++kk) {
            int ko = 32 * kk + kq8;
            float4 a = {0.f, 0.f, 0.f, 0.f}, b = a;
            if (xvalid) {
                a = ((const float4*)(xrow0 + ko))[0];
                b = ((const float4*)(xrow0 + ko))[1];
            }
            xq[2 * kk] = a; xq[2 * kk + 1] = b;
        }
        #pragma unroll
        for (int kk = 0; kk < 4; ++kk) {
            int ko = 32 * kk + kq8;
            bf16x8 av = cvt8r(xq[2 * kk], xq[2 * kk + 1]);
            accR  = MFMA16(av, *(const bf16x8*)(Wx + (size_t)cl * WXST + ko),         accR);
            accZ  = MFMA16(av, *(const bf16x8*)(Wx + (size_t)(64 + cl) * WXST + ko),  accZ);
            accNX = MFMA16(av, *(const bf16x8*)(Wx + (size_t)(128 + cl) * WXST + ko), accNX);
        }
    }

    float hold[4] = {0.f, 0.f, 0.f, 0.f};

    const unsigned hv_voff = ((unsigned)(nb + mi) * HD + (unsigned)kq8) * 2u;
    const unsigned st_voff = ((unsigned)(nb + (ln >> 4) * 4) * HD + (unsigned)ch) * 2u;
    const unsigned tg_self = (unsigned)(g * 32 + s * 4 + w) * 64u;
    const unsigned tg_poll = (unsigned)(g * 32 + (ln & 31)) * 64u;

    #pragma unroll 1
    for (int t = 0; t < TS; ++t) {
        __bf16* hcur = (t & 1) ? h1buf : h0buf;
        __bf16* hnxt = (t & 1) ? h0buf : h1buf;

        // ---- wait for h_t: 32 per-wave tags polled in parallel ----
        for (;;) {
            int v = tagload_a(tags, tg_poll);
            if (__all((ln < 32) ? (v >= t) : 1)) break;
        }

        // ---- h_t -> 16 frags (one bundled load), 48 MFMA ----
        {
            f32x4 hv[16];
            loadh16_a(hcur, hv_voff, hv);
            #pragma unroll
            for (int kk = 0; kk < 16; ++kk) {
                bf16x8 av = __builtin_bit_cast(bf16x8, hv[kk]);
                accR  = MFMA16(av, wR[kk], accR);
                accZ  = MFMA16(av, wZ[kk], accZ);
                accNH = MFMA16(av, wN[kk], accNH);
            }
        }

        // ---- gates + h update + publish (ack deferred) ----
        {
            unsigned pv[4];
            #pragma unroll
            for (int e = 0; e < 4; ++e) {
                float rv = sig_(accR[e] + bR);
                float zv = sig_(accZ[e] + bZ);
                float nv = tanh_(accNX[e] + bNX + rv * (accNH[e] + bNH));
                float hnew = (1.f - zv) * nv + zv * hold[e];
                hold[e] = hnew;
                pv[e] = (unsigned)__builtin_bit_cast(unsigned short, (__bf16)hnew);
            }
            storeh4_a(hnxt, st_voff, pv[0], pv[1], pv[2], pv[3]);   // in flight
        }

        // ---- prefetch x_{t+1} (cached; overlaps the store ack) ----
        float4 xq[8];
        #pragma unroll
        for (int kk = 0; kk < 8; ++kk) xq[kk] = make_float4(0.f, 0.f, 0.f, 0.f);
        if (t + 1 < TS && xvalid) {
            const float* xp = xrow0 + (size_t)(t + 1) * NN * FD;
            #pragma unroll
            for (int kk = 0; kk < 4; ++kk) {
                int ko = 32 * kk + kq8;
                xq[2 * kk]     = ((const float4*)(xp + ko))[0];
                xq[2 * kk + 1] = ((const float4*)(xp + ko))[1];
            }
        }

        asm volatile("s_waitcnt vmcnt(0)" ::: "memory");   // h acked at LLC (+x loaded)
        if (ln == 0) tagstore_a(tags, tg_self, t + 1);

        // ---- slack window: x-part MFMAs for t+1 (fresh accumulators) ----
        accR = {0.f, 0.f, 0.f, 0.f}; accZ = accR; accNX = accR; accNH = accR;
        if (t + 1 < TS) {
            #pragma unroll
            for (int kk = 0; kk < 4; ++kk) {
                int ko = 32 * kk + kq8;
                bf16x8 av = cvt8r(xq[2 * kk], xq[2 * kk + 1]);
                accR  = MFMA16(av, *(const bf16x8*)(Wx + (size_t)cl * WXST + ko),         accR);
                accZ  = MFMA16(av, *(const bf16x8*)(Wx + (size_t)(64 + cl) * WXST + ko),  accZ);
                accNX = MFMA16(av, *(const bf16x8*)(Wx + (size_t)(128 + cl) * WXST + ko), accNX);
            }
        }
    }

    // ---- epilogue: final h -> enc (fp32) ----
    #pragma unroll
    for (int e = 0; e < 4; ++e) {
        int row = (ln >> 4) * 4 + e;
        if (nb + row < NN)
            enc[(size_t)(nb + row) * HD + ch] = hold[e];
    }
}

// ===================== epilogue (tiny) =====================

__global__ void e1_gnn_in(const float* __restrict__ enc, const float* __restrict__ flat,
                          const float* __restrict__ emb, const float* __restrict__ fW,
                          const float* __restrict__ fb, float* __restrict__ gnn)
{
    int i = blockIdx.x, tid = threadIdx.x;
    const float4* src = (const float4*)(enc + (size_t)i * HD);
    float4* dst = (float4*)(gnn + (size_t)i * GIN);
    dst[tid] = src[tid];
    if (tid < 64) {
        float acc = fb[tid];
        const float* w  = fW + tid * 32;
        const float* fl = flat + i * 32;
        #pragma unroll
        for (int k = 0; k < 32; ++k) acc = fmaf(fl[k], w[k], acc);
        gnn[(size_t)i * GIN + HD + tid] = acc;
    }
    gnn[(size_t)i * GIN + HD + 64 + tid] = emb[(size_t)i * FD + tid];
}

__global__ void e2a_norm(const float* __restrict__ emb, float* __restrict__ mx)
{
    int j = threadIdx.x;
    if (j < NN) {
        float acc = 0.f;
        const float* e = emb + (size_t)j * FD;
        for (int d = 0; d < FD; ++d) acc = fmaf(e[d], e[d], acc);
        mx[j] = fmaxf(sqrtf(acc), 1e-8f);
    }
}

__global__ void e2b_knn(const float* __restrict__ emb, const float* __restrict__ mx,
                        int* __restrict__ tgt)
{
    int i = blockIdx.x, tid = threadIdx.x;   // 128 threads
    __shared__ float ei[FD];
    __shared__ float srow[NN];
    ei[tid] = emb[(size_t)i * FD + tid];
    __syncthreads();
    if (tid < NN) {
        float acc = 0.f;
        const float* e = emb + (size_t)tid * FD;
        for (int d = 0; d < FD; ++d) acc = fmaf(ei[d], e[d], acc);
        float sim = acc / (mx[i] * mx[tid]);
        srow[tid] = (tid == i) ? 0.f : sim;
    }
    __syncthreads();
    if (tid == 0) {
        for (int t = 0; t < KNN; ++t) {
            float best = -1e30f; int bi = 0;
            for (int j = 0; j < NN; ++j) { float v = srow[j]; if (v > best) { best = v; bi = j; } }
            srow[bi] = -1e30f;
            tgt[i * KNN + t] = bi;
        }
    }
}

__global__ void e3_agg(const float* __restrict__ xin, const int* __restrict__ tgt,
                       float* __restrict__ agg, float* __restrict__ cnt, int D)
{
    int e = blockIdx.x, src = e >> 3, tg = tgt[e];
    for (int d = threadIdx.x; d < D; d += blockDim.x)
        atomicAdd(&agg[(size_t)tg * D + d], xin[(size_t)src * D + d]);
    if (threadIdx.x == 0) atomicAdd(&cnt[tg], 1.0f);
}

__global__ void e4_sage(const float* __restrict__ agg, const float* __restrict__ xin,
                        const float* __restrict__ cnt,
                        const float* __restrict__ Wl, const float* __restrict__ Wr,
                        const float* __restrict__ b, float* __restrict__ out,
                        int Din, int Dout, int dorelu)
{
    int j = blockIdx.x, o = threadIdx.x;
    extern __shared__ float sm[];
    float* la = sm;
    float* lx = sm + Din;
    for (int d = o; d < Din; d += blockDim.x) {
        la[d] = agg[(size_t)j * Din + d];
        lx[d] = xin[(size_t)j * Din + d];
    }
    __syncthreads();
    float inv = 1.f / fmaxf(cnt[j], 1.f);
    float acc1 = 0.f, acc2 = 0.f;
    const float* wl = Wl + (size_t)o * Din;
    const float* wr = Wr + (size_t)o * Din;
    for (int k = 0; k < Din; ++k) {
        acc1 = fmaf(la[k], wl[k], acc1);
        acc2 = fmaf(lx[k], wr[k], acc2);
    }
    float v = fmaf(acc1, inv, acc2) + b[o];
    if (dorelu) v = fmaxf(v, 0.f);
    out[(size_t)j * Dout + o] = v;
}

__global__ void e7_out(const float* __restrict__ g, const float* __restrict__ enc,
                       const float* __restrict__ oW, const float* __restrict__ ob,
                       float* __restrict__ out)
{
    int j = threadIdx.x;
    if (j < NN) {
        float acc = ob[0];
        const float* gr = g + (size_t)j * GOUT;
        for (int d = 0; d < GOUT; ++d) acc = fmaf(gr[d], oW[d], acc);
        const float* er = enc + (size_t)j * HD;
        for (int d = 0; d < HD; ++d) acc = fmaf(er[d], oW[GOUT + d], acc);
        out[j] = 1.f / (1.f + expf(-acc));
    }
}

// ===================== launch =====================
extern "C" void kernel_launch(void* const* d_in, const int* in_sizes, int n_in,
                              void* d_out, int out_size, void* d_ws, size_t ws_size,
                              hipStream_t stream)
{
    const float* x    = (const float*)d_in[0];
    const float* flat = (const float*)d_in[1];
    const float* emb  = (const float*)d_in[2];
    const float* Wih  = (const float*)d_in[3];
    const float* Whh  = (const float*)d_in[4];
    const float* bih  = (const float*)d_in[5];
    const float* bhh  = (const float*)d_in[6];
    const float* fW   = (const float*)d_in[7];
    const float* fb   = (const float*)d_in[8];
    const float* s1Wl = (const float*)d_in[9];
    const float* s1Wr = (const float*)d_in[10];
    const float* s1b  = (const float*)d_in[11];
    const float* s2Wl = (const float*)d_in[12];
    const float* s2Wr = (const float*)d_in[13];
    const float* s2b  = (const float*)d_in[14];
    const float* oW   = (const float*)d_in[15];
    const float* ob   = (const float*)d_in[16];
    float* out = (float*)d_out;

    // workspace layout (bytes). Zero zone first -> single memset.
    char* p = (char*)d_ws;
    __bf16* h0buf = (__bf16*)(p + 0);        // 114688  [zero: h0]
    float*  agg1  = (float*)(p + 114688);    // 281600  [zero]
    float*  agg2  = (float*)(p + 396288);    // 102400  [zero]
    float*  cnt1  = (float*)(p + 498688);    // 448     [zero]
    float*  cnt2  = (float*)(p + 499136);    // 448     [zero]
    int*    tags  = (int*)  (p + 499584);    // 14336   [zero: 224 x 64B]
    __bf16* h1buf = (__bf16*)(p + 513920);   // 114688
    float*  enc   = (float*)(p + 628608);    // 229376
    float*  gnn   = (float*)(p + 857984);    // 281600
    float*  h1s   = (float*)(p + 1139584);   // 102400
    float*  gbuf  = (float*)(p + 1241984);   // 51200
    float*  mx    = (float*)(p + 1293184);   // 448
    int*    tgt   = (int*)  (p + 1293632);   // 3200
    // total ~1.30 MiB

    (void)hipMemsetAsync(d_ws, 0, 513920, stream);

    gru_kernel<<<NG * NSL, 256, 0, stream>>>(x, Wih, Whh, bih, bhh, h0buf, h1buf, enc, tags);
    e1_gnn_in<<<NN, 128, 0, stream>>>(enc, flat, emb, fW, fb, gnn);
    e2a_norm<<<1, 128, 0, stream>>>(emb, mx);
    e2b_knn<<<NN, 128, 0, stream>>>(emb, mx, tgt);
    e3_agg<<<NN * KNN, 256, 0, stream>>>(gnn, tgt, agg1, cnt1, GIN);
    e4_sage<<<NN, GH, 2 * GIN * sizeof(float), stream>>>(agg1, gnn, cnt1, s1Wl, s1Wr, s1b, h1s, GIN, GH, 1);
    e3_agg<<<NN * KNN, 256, 0, stream>>>(h1s, tgt, agg2, cnt2, GH);
    e4_sage<<<NN, GOUT, 2 * GH * sizeof(float), stream>>>(agg2, h1s, cnt2, s2Wl, s2Wr, s2b, gbuf, GH, GOUT, 0);
    e7_out<<<1, 128, 0, stream>>>(gbuf, enc, oW, ob, out);
}